// Round 6
// baseline (210.297 us; speedup 1.0000x reference)
//
#include <hip/hip_runtime.h>
#include <hip/hip_bf16.h>
#include <stdint.h>

#define NB 8
#define NP 12000
#define NM 32
#define NF 9
#define NC 64
#define NX 144
#define NCELL (144*144)

#define PPW 8                        // pillars per wave
#define FEAT_WAVES ((NB*NP)/PPW)     // 12000
#define FEAT_BLOCKS (FEAT_WAVES/4)   // 3000 blocks x 4 waves

typedef __attribute__((ext_vector_type(8)))  short bfrag8;    // 8 bf16
typedef __attribute__((ext_vector_type(16))) float accf16;    // 16 f32 acc
typedef float f32x4u __attribute__((ext_vector_type(4), aligned(4)));  // dword-aligned vec4

// ws layout:
//   [0,2048)        btab: 2 c-tiles x 64 lanes x 8 bf16 (B-frag order, BN-folded)
//   [2048,2304)     shift[c]
//   [4096,667648)   winner[b][cell] (8*20736 ints)
//   [668672,+24.576M) feat_ws[(b*NP+p)*64 + c]
#define WS_BTAB  0
#define WS_SHIFT 2048
#define WS_WIN   4096
#define WS_FEAT  668672
#define WS_NEED  (WS_FEAT + (size_t)NB*NP*NC*4)

// Pass 1: last-write-wins winner (largest p wins, numpy fancy-assign) +
// BN-folded weight table prep in block 0.
__global__ void winner_prep_kernel(const int* __restrict__ idx, int* __restrict__ winner,
                                   const float* __restrict__ conv_w,
                                   const float* __restrict__ gamma,
                                   const float* __restrict__ beta,
                                   const float* __restrict__ mean,
                                   const float* __restrict__ var,
                                   unsigned short* __restrict__ btab,
                                   float* __restrict__ shift)
{
    int t = blockIdx.x * blockDim.x + threadIdx.x;
    if (t < NB * NP) {
        int b = t / NP;
        int p = t - b * NP;
        int y = idx[t * 3 + 1];
        int x = idx[t * 3 + 2];
        x = x < 0 ? 0 : (x > 143 ? 143 : x);
        y = y < 0 ? 0 : (y > 143 ? 143 : y);
        atomicMax(&winner[b * NCELL + y * NX + x], p);   // init = -1
    }
    if (blockIdx.x == 0) {
        int tt = threadIdx.x;
        if (tt < 128) {
            int ct = tt >> 6, L = tt & 63;
            int c  = ct * 32 + (L & 31);
            int kq = L >> 5;
            float sc = gamma[c] * rsqrtf(var[c] + 1e-5f);
            unsigned short* dst = btab + (ct * 64 + L) * 8;
            #pragma unroll
            for (int j = 0; j < 8; ++j) {
                int k = kq * 8 + j;
                float w = (k < NF) ? conv_w[c * NF + k] * sc : 0.f;
                __hip_bfloat16 h = __float2bfloat16(w);
                dst[j] = *(unsigned short*)&h;
            }
        }
        if (tt < NC) {
            float sc = gamma[tt] * rsqrtf(var[tt] + 1e-5f);
            shift[tt] = beta[tt] - mean[tt] * sc;
        }
    }
}

__device__ __forceinline__ float max16(const accf16& a) {
    float t0 = fmaxf(fmaxf(a[0], a[1]),  fmaxf(a[2], a[3]));
    float t1 = fmaxf(fmaxf(a[4], a[5]),  fmaxf(a[6], a[7]));
    float t2 = fmaxf(fmaxf(a[8], a[9]),  fmaxf(a[10], a[11]));
    float t3 = fmaxf(fmaxf(a[12], a[13]), fmaxf(a[14], a[15]));
    return fmaxf(fmaxf(t0, t1), fmaxf(t2, t3));
}

// Pass 2: dense streaming conv+max over ALL pillars. No LDS, no barrier.
// Per pillar, lane L loads row (L&31)'s 9 floats with 3 VMEM ops
// (dwordx4 + dwordx4 + dword; dword alignment is sufficient for gfx950
// global vector loads), batched 4 pillars ahead of use for MLP. 2 MFMA
// (c-tiles of 32), tree max over 16 regs + shfl_xor(32), BN shift + relu,
// 256B coalesced store.
template <bool COMPACT>
__global__ void __launch_bounds__(256) feat_dense_kernel(
    const float* __restrict__ pillars,
    const unsigned short* __restrict__ btab,
    const float* __restrict__ shift,
    const int*   __restrict__ idx,       // fallback path only
    const int*   __restrict__ winner,    // fallback path only
    float* __restrict__ feat_ws,
    float* __restrict__ out)
{
    int tid  = threadIdx.x;
    int lane = tid & 63;
    int wave = blockIdx.x * 4 + (tid >> 6);
    int row  = lane & 31;
    int kq   = lane >> 5;

    bfrag8 b0 = *(const bfrag8*)(btab + lane * 8);          // c 0..31
    bfrag8 b1 = *(const bfrag8*)(btab + (64 + lane) * 8);   // c 32..63
    float  sh = shift[lane];
    accf16 z  = {};

    const float* wbase = pillars + (size_t)wave * (PPW * NM * NF) + row * NF;

    #pragma unroll
    for (int g = 0; g < PPW / 4; ++g) {
        // ---- load phase: 4 pillars' fragments issued before any use ----
        f32x4u lo[4], hi[4];
        float  e8[4];
        #pragma unroll
        for (int i = 0; i < 4; ++i) {
            const float* base = wbase + (size_t)(g * 4 + i) * (NM * NF);
            lo[i] = *(const f32x4u*)(base);        // f0..f3
            hi[i] = *(const f32x4u*)(base + 4);    // f4..f7
            e8[i] = base[8];                       // f8
        }
        // ---- compute phase ----
        #pragma unroll
        for (int i = 0; i < 4; ++i) {
            int pil = wave * PPW + g * 4 + i;
            // A-frag: kq=0 -> f0..f7 ; kq=1 -> {f8, 0...} (K padded 9->16)
            float s[8];
            s[0] = kq ? e8[i] : lo[i][0];
            s[1] = kq ? 0.f   : lo[i][1];
            s[2] = kq ? 0.f   : lo[i][2];
            s[3] = kq ? 0.f   : lo[i][3];
            s[4] = kq ? 0.f   : hi[i][0];
            s[5] = kq ? 0.f   : hi[i][1];
            s[6] = kq ? 0.f   : hi[i][2];
            s[7] = kq ? 0.f   : hi[i][3];
            bfrag8 a;
            #pragma unroll
            for (int j = 0; j < 8; ++j) {
                __hip_bfloat16 h = __float2bfloat16(s[j]);
                a[j] = *(short*)&h;
            }
            accf16 acc0 = __builtin_amdgcn_mfma_f32_32x32x16_bf16(a, b0, z, 0, 0, 0);
            accf16 acc1 = __builtin_amdgcn_mfma_f32_32x32x16_bf16(a, b1, z, 0, 0, 0);

            float v0 = max16(acc0);
            float v1 = max16(acc1);
            v0 = fmaxf(v0, __shfl_xor(v0, 32));
            v1 = fmaxf(v1, __shfl_xor(v1, 32));
            float r = (lane < 32) ? v0 : v1;    // col=lane&31 -> channel = lane
            r += sh;
            r = r > 0.f ? r : 0.f;

            if (COMPACT) {
                feat_ws[(size_t)pil * NC + lane] = r;
            } else {
                int b = pil / NP, p = pil - b * NP;
                int y = idx[pil * 3 + 1], x = idx[pil * 3 + 2];
                x = x < 0 ? 0 : (x > 143 ? 143 : x);
                y = y < 0 ? 0 : (y > 143 ? 143 : y);
                int cell = y * NX + x;
                if (winner[b * NCELL + cell] == p)
                    out[((size_t)(b * NC + lane)) * NCELL + cell] = r;
            }
        }
    }
}

// Pass 3: cell-major coalesced canvas write. thread = (b, channel-quarter q,
// 4 consecutive cells): 4 LLC line-gathers (reused across k) + 16 coalesced
// float4 stores.
__global__ void __launch_bounds__(256) scatter_kernel(
    const int* __restrict__ winner,
    const float* __restrict__ feat_ws,
    float* __restrict__ out)
{
    int t  = blockIdx.x * blockDim.x + threadIdx.x;   // [0, NB*4*(NCELL/4))
    int c4 = t % (NCELL / 4);
    int bq = t / (NCELL / 4);
    int q  = bq & 3;
    int b  = bq >> 2;
    int cellbase = c4 * 4;

    int4 wv = *(const int4*)(winner + b * NCELL + cellbase);
    long long base0 = wv.x < 0 ? -1 : ((long long)(b * NP + wv.x)) * NC;
    long long base1 = wv.y < 0 ? -1 : ((long long)(b * NP + wv.y)) * NC;
    long long base2 = wv.z < 0 ? -1 : ((long long)(b * NP + wv.z)) * NC;
    long long base3 = wv.w < 0 ? -1 : ((long long)(b * NP + wv.w)) * NC;

    const float4 zf = make_float4(0.f, 0.f, 0.f, 0.f);
    #pragma unroll
    for (int k = 0; k < 4; ++k) {
        int c0 = q * 16 + k * 4;
        float4 f0 = base0 < 0 ? zf : *(const float4*)(feat_ws + base0 + c0);
        float4 f1 = base1 < 0 ? zf : *(const float4*)(feat_ws + base1 + c0);
        float4 f2 = base2 < 0 ? zf : *(const float4*)(feat_ws + base2 + c0);
        float4 f3 = base3 < 0 ? zf : *(const float4*)(feat_ws + base3 + c0);
        float* o = out + ((size_t)(b * NC + c0)) * NCELL + cellbase;
        *(float4*)(o + 0ULL * NCELL) = make_float4(f0.x, f1.x, f2.x, f3.x);
        *(float4*)(o + 1ULL * NCELL) = make_float4(f0.y, f1.y, f2.y, f3.y);
        *(float4*)(o + 2ULL * NCELL) = make_float4(f0.z, f1.z, f2.z, f3.z);
        *(float4*)(o + 3ULL * NCELL) = make_float4(f0.w, f1.w, f2.w, f3.w);
    }
}

extern "C" void kernel_launch(void* const* d_in, const int* in_sizes, int n_in,
                              void* d_out, int out_size, void* d_ws, size_t ws_size,
                              hipStream_t stream) {
    const float* pillars = (const float*)d_in[0];
    const int*   idx     = (const int*)d_in[1];
    const float* conv_w  = (const float*)d_in[2];
    const float* gamma   = (const float*)d_in[3];
    const float* beta    = (const float*)d_in[4];
    const float* mean    = (const float*)d_in[5];
    const float* var     = (const float*)d_in[6];
    float* out = (float*)d_out;

    char* ws = (char*)d_ws;
    unsigned short* btab    = (unsigned short*)(ws + WS_BTAB);
    float*          shift   = (float*)(ws + WS_SHIFT);
    int*            winner  = (int*)(ws + WS_WIN);
    float*          feat_ws = (float*)(ws + WS_FEAT);

    const bool compact = ws_size >= WS_NEED;   // constant per session -> graph-safe

    hipMemsetAsync(winner, 0xFF, (size_t)NB * NCELL * sizeof(int), stream);
    winner_prep_kernel<<<(NB * NP + 255) / 256, 256, 0, stream>>>(
        idx, winner, conv_w, gamma, beta, mean, var, btab, shift);

    if (compact) {
        feat_dense_kernel<true><<<FEAT_BLOCKS, 256, 0, stream>>>(
            pillars, btab, shift, idx, winner, feat_ws, out);
        int sthreads = NB * 4 * (NCELL / 4);             // 165,888 = 648 blocks
        scatter_kernel<<<sthreads / 256, 256, 0, stream>>>(winner, feat_ws, out);
    } else {
        hipMemsetAsync(out, 0, (size_t)out_size * sizeof(float), stream);
        feat_dense_kernel<false><<<FEAT_BLOCKS, 256, 0, stream>>>(
            pillars, btab, shift, idx, winner, feat_ws, out);
    }
}

// Round 7
// 208.672 us; speedup vs baseline: 1.0078x; 1.0078x over previous
//
#include <hip/hip_runtime.h>
#include <hip/hip_bf16.h>
#include <stdint.h>

#define NB 8
#define NP 12000
#define NM 32
#define NF 9
#define NC 64
#define NX 144
#define NCELL (144*144)          // 20736 = 64*324

#define PPW 8                    // pillars per wave
#define FEAT_WAVES ((NB*NP)/PPW) // 12000 (1500/batch -> no batch straddle)
#define FEAT_BLOCKS (FEAT_WAVES/4)
#define TILES_PER_B (NCELL/64)   // 324

typedef __attribute__((ext_vector_type(8)))  short bfrag8;
typedef __attribute__((ext_vector_type(16))) float accf16;
typedef float f32x4u __attribute__((ext_vector_type(4), aligned(4)));

// ws layout:
//   [0,2048)        btab: 2 c-tiles x 64 lanes x 8 bf16 (B-frag, BN-folded)
//   [2048,2304)     shift[c]
//   [4096,667648)   winner[b][cell] (8*20736 ints)
//   [667648,+42.47M) feat_cell[(b*NCELL+cell)*64 + c]  (winner cells only)
#define WS_BTAB  0
#define WS_SHIFT 2048
#define WS_WIN   4096
#define WS_CELL  667648
#define WS_NEED  (WS_CELL + (size_t)NB*NCELL*NC*4)

// Pass 1: last-write-wins winner (largest p wins) + BN-folded weight prep.
__global__ void winner_prep_kernel(const int* __restrict__ idx, int* __restrict__ winner,
                                   const float* __restrict__ conv_w,
                                   const float* __restrict__ gamma,
                                   const float* __restrict__ beta,
                                   const float* __restrict__ mean,
                                   const float* __restrict__ var,
                                   unsigned short* __restrict__ btab,
                                   float* __restrict__ shift)
{
    int t = blockIdx.x * blockDim.x + threadIdx.x;
    if (t < NB * NP) {
        int b = t / NP;
        int p = t - b * NP;
        int y = idx[t * 3 + 1];
        int x = idx[t * 3 + 2];
        x = x < 0 ? 0 : (x > 143 ? 143 : x);
        y = y < 0 ? 0 : (y > 143 ? 143 : y);
        atomicMax(&winner[b * NCELL + y * NX + x], p);   // init = -1
    }
    if (blockIdx.x == 0) {
        int tt = threadIdx.x;
        if (tt < 128) {
            int ct = tt >> 6, L = tt & 63;
            int c  = ct * 32 + (L & 31);
            int kq = L >> 5;
            float sc = gamma[c] * rsqrtf(var[c] + 1e-5f);
            unsigned short* dst = btab + (ct * 64 + L) * 8;
            #pragma unroll
            for (int j = 0; j < 8; ++j) {
                int k = kq * 8 + j;
                float w = (k < NF) ? conv_w[c * NF + k] * sc : 0.f;
                __hip_bfloat16 h = __float2bfloat16(w);
                dst[j] = *(unsigned short*)&h;
            }
        }
        if (tt < NC) {
            float sc = gamma[tt] * rsqrtf(var[tt] + 1e-5f);
            shift[tt] = beta[tt] - mean[tt] * sc;
        }
    }
}

__device__ __forceinline__ float max16(const accf16& a) {
    float t0 = fmaxf(fmaxf(a[0], a[1]),  fmaxf(a[2], a[3]));
    float t1 = fmaxf(fmaxf(a[4], a[5]),  fmaxf(a[6], a[7]));
    float t2 = fmaxf(fmaxf(a[8], a[9]),  fmaxf(a[10], a[11]));
    float t3 = fmaxf(fmaxf(a[12], a[13]), fmaxf(a[14], a[15]));
    return fmaxf(fmaxf(t0, t1), fmaxf(t2, t3));
}

// Pass 2: dense streaming conv+max. Winner/cell metadata for all 8 pillars
// hoisted to the top (wave-uniform, independent chains). Winner pillars write
// their 64 channels as one 256B aligned row to feat_cell[b][cell][*].
template <bool COMPACT>
__global__ void __launch_bounds__(256) feat_dense_kernel(
    const float* __restrict__ pillars,
    const unsigned short* __restrict__ btab,
    const float* __restrict__ shift,
    const int*   __restrict__ idx,
    const int*   __restrict__ winner,
    float* __restrict__ feat_cell,
    float* __restrict__ out)
{
    int tid  = threadIdx.x;
    int lane = tid & 63;
    int wave = blockIdx.x * 4 + (tid >> 6);
    int row  = lane & 31;
    int kq   = lane >> 5;
    int b    = wave / (NP / PPW);            // 1500 waves per batch, no straddle

    bfrag8 b0 = *(const bfrag8*)(btab + lane * 8);
    bfrag8 b1 = *(const bfrag8*)(btab + (64 + lane) * 8);
    float  sh = shift[lane];
    accf16 z  = {};

    // hoisted per-pillar metadata (wave-uniform)
    int cellv[PPW];
    bool winv[PPW];
    #pragma unroll
    for (int i = 0; i < PPW; ++i) {
        int pil = wave * PPW + i;
        int y = idx[pil * 3 + 1];
        int x = idx[pil * 3 + 2];
        x = x < 0 ? 0 : (x > 143 ? 143 : x);
        y = y < 0 ? 0 : (y > 143 ? 143 : y);
        int cell = y * NX + x;
        cellv[i] = cell;
        winv[i]  = (winner[b * NCELL + cell] == pil - b * NP);
    }

    const float* wbase = pillars + (size_t)wave * (PPW * NM * NF) + row * NF;

    #pragma unroll
    for (int g = 0; g < PPW / 4; ++g) {
        f32x4u lo[4], hi[4];
        float  e8[4];
        #pragma unroll
        for (int i = 0; i < 4; ++i) {
            const float* base = wbase + (size_t)(g * 4 + i) * (NM * NF);
            lo[i] = *(const f32x4u*)(base);
            hi[i] = *(const f32x4u*)(base + 4);
            e8[i] = base[8];
        }
        #pragma unroll
        for (int i = 0; i < 4; ++i) {
            int pi = g * 4 + i;
            float s[8];
            s[0] = kq ? e8[i] : lo[i][0];
            s[1] = kq ? 0.f   : lo[i][1];
            s[2] = kq ? 0.f   : lo[i][2];
            s[3] = kq ? 0.f   : lo[i][3];
            s[4] = kq ? 0.f   : hi[i][0];
            s[5] = kq ? 0.f   : hi[i][1];
            s[6] = kq ? 0.f   : hi[i][2];
            s[7] = kq ? 0.f   : hi[i][3];
            bfrag8 a;
            #pragma unroll
            for (int j = 0; j < 8; ++j) {
                __hip_bfloat16 h = __float2bfloat16(s[j]);
                a[j] = *(short*)&h;
            }
            accf16 acc0 = __builtin_amdgcn_mfma_f32_32x32x16_bf16(a, b0, z, 0, 0, 0);
            accf16 acc1 = __builtin_amdgcn_mfma_f32_32x32x16_bf16(a, b1, z, 0, 0, 0);

            float v0 = max16(acc0);
            float v1 = max16(acc1);
            v0 = fmaxf(v0, __shfl_xor(v0, 32));
            v1 = fmaxf(v1, __shfl_xor(v1, 32));
            float r = (lane < 32) ? v0 : v1;   // channel = lane
            r += sh;
            r = r > 0.f ? r : 0.f;

            if (winv[pi]) {                    // wave-uniform branch
                if (COMPACT) {
                    feat_cell[((size_t)(b * NCELL + cellv[pi])) * NC + lane] = r;
                } else {
                    out[((size_t)(b * NC + lane)) * NCELL + cellv[pi]] = r;
                }
            }
        }
    }
}

// Pass 3: dense LDS transpose. Block = (b, 64-cell tile). Read feat_cell
// coalesced (loser lanes exec-masked -> load skipped), zero-fill losers,
// transpose via LDS, write out coalesced float4. Covers every out element.
__global__ void __launch_bounds__(256) scatter_t_kernel(
    const int* __restrict__ winner,
    const float* __restrict__ feat_cell,
    float* __restrict__ out)
{
    __shared__ float ld[NC * 68];            // stride 68 floats, 17.4 KB
    int tile = blockIdx.x;                   // [0, NB*324)
    int b    = tile / TILES_PER_B;
    int cb   = (tile - b * TILES_PER_B) * 64;
    int t    = threadIdx.x;

    // load phase: thread t -> cell = t>>2, quarter q = t&3 (16 ch as 4 float4)
    {
        int cell = t >> 2, q = t & 3;
        int w = winner[b * NCELL + cb + cell];
        const f32x4u* src = (const f32x4u*)(feat_cell +
                             ((size_t)(b * NCELL + cb + cell)) * NC);
        #pragma unroll
        for (int k = 0; k < 4; ++k) {
            f32x4u v = {0.f, 0.f, 0.f, 0.f};
            if (w >= 0) v = src[q * 4 + k];  // masked load: losers skip fetch
            int c = q * 16 + k * 4;
            ld[(c + 0) * 68 + cell] = v[0];  // transpose on LDS write
            ld[(c + 1) * 68 + cell] = v[1];
            ld[(c + 2) * 68 + cell] = v[2];
            ld[(c + 3) * 68 + cell] = v[3];
        }
    }
    __syncthreads();
    // write phase: thread t -> c = t>>2, quarter qq = t&3 (16 cells as 4 float4)
    {
        int c = t >> 2, qq = t & 3;
        float* o = out + ((size_t)(b * NC + c)) * NCELL + cb + qq * 16;
        const float* lrow = ld + c * 68 + qq * 16;
        #pragma unroll
        for (int k = 0; k < 4; ++k) {
            *(f32x4u*)(o + k * 4) = *(const f32x4u*)(lrow + k * 4);
        }
    }
}

extern "C" void kernel_launch(void* const* d_in, const int* in_sizes, int n_in,
                              void* d_out, int out_size, void* d_ws, size_t ws_size,
                              hipStream_t stream) {
    const float* pillars = (const float*)d_in[0];
    const int*   idx     = (const int*)d_in[1];
    const float* conv_w  = (const float*)d_in[2];
    const float* gamma   = (const float*)d_in[3];
    const float* beta    = (const float*)d_in[4];
    const float* mean    = (const float*)d_in[5];
    const float* var     = (const float*)d_in[6];
    float* out = (float*)d_out;

    char* ws = (char*)d_ws;
    unsigned short* btab      = (unsigned short*)(ws + WS_BTAB);
    float*          shift     = (float*)(ws + WS_SHIFT);
    int*            winner    = (int*)(ws + WS_WIN);
    float*          feat_cell = (float*)(ws + WS_CELL);

    const bool compact = ws_size >= WS_NEED;   // constant per session

    hipMemsetAsync(winner, 0xFF, (size_t)NB * NCELL * sizeof(int), stream);
    winner_prep_kernel<<<(NB * NP + 255) / 256, 256, 0, stream>>>(
        idx, winner, conv_w, gamma, beta, mean, var, btab, shift);

    if (compact) {
        feat_dense_kernel<true><<<FEAT_BLOCKS, 256, 0, stream>>>(
            pillars, btab, shift, idx, winner, feat_cell, out);
        scatter_t_kernel<<<NB * TILES_PER_B, 256, 0, stream>>>(
            winner, feat_cell, out);
    } else {
        hipMemsetAsync(out, 0, (size_t)out_size * sizeof(float), stream);
        feat_dense_kernel<false><<<FEAT_BLOCKS, 256, 0, stream>>>(
            pillars, btab, shift, idx, winner, feat_cell, out);
    }
}